// Round 7
// baseline (281.338 us; speedup 1.0000x reference)
//
#include <hip/hip_runtime.h>

#define BCNT 16
#define TT 1024
#define DIN 384
#define H1 1024
#define H2 1024
#define KW 9

#define NB_TPW (BCNT * (H2 / 32))                              // 512
#define N4_CVT ((BCNT * TT * DIN + H1 * DIN + DIN * H2) / 4)   // 1,769,472
#define NB_CVT (N4_CVT / 256)                                  // 6912 (exact)
#define NB_NORM (BCNT * KW)                                    // 144

typedef __attribute__((ext_vector_type(8))) short bhalf8;   // 8 bf16 in 4 VGPRs
typedef __attribute__((ext_vector_type(4))) float f32x4;

typedef const __attribute__((address_space(1))) void* gas_ptr;
typedef __attribute__((address_space(3))) void* lds_ptr;

__device__ __forceinline__ float bf2f(unsigned short u) {
    return __uint_as_float(((unsigned int)u) << 16);
}
__device__ __forceinline__ unsigned short f2bf(float f) {
    unsigned int u = __float_as_uint(f);
    unsigned int r = (u + 0x7FFFu + ((u >> 16) & 1u)) >> 16;  // RNE
    return (unsigned short)r;
}
// mish(x) = x*tanh(log1p(e^x)) = x*(u^2+2u)/(u^2+2u+2), u=e^x (exact algebra)
__device__ __forceinline__ float mish_f(float x) {
    if (x > 20.f) return x;
    float u = __expf(x);
    float n = u * u + 2.f * u;
    return x * n / (n + 2.f);
}

// ---------------- fused prep kernel: 3 independent sections by blockIdx ----------------
// [0, NB_TPW):            per-(b, o-strip-of-32) transpose+scale of p_w + inv_np (no atomics)
// [NB_TPW, +NB_CVT):      f32->bf16 cvt of input|w1_w|w2_w (exact coverage)
// [.., +NB_NORM):         norm_d[b,k] = max(||d_w[b,:,k]||, 1e-12)
__global__ __launch_bounds__(256) void k_prep(
    const float* __restrict__ input, unsigned short* __restrict__ inbf,
    const float* __restrict__ w1_w, unsigned short* __restrict__ w1bf,
    const float* __restrict__ w2_w, unsigned short* __restrict__ w2bf,
    const float* __restrict__ p_w, const float* __restrict__ p_g,
    unsigned short* __restrict__ pwTu, float* __restrict__ inv_np,
    const float* __restrict__ d_w, float* __restrict__ norm_d) {
    const int blk = blockIdx.x;
    if (blk < NB_TPW) {
        // --- transpose + scale + column-norm of p_w; block owns (b, o0..o0+31), all c ---
        __shared__ float tile[32][33];
        __shared__ float red[8][32];
        const int tx = threadIdx.x & 31, ty = threadIdx.x >> 5;  // 32 x 8
        const int b = blk >> 5, o0 = (blk & 31) * 32;
        float s = 0.f;
        for (int c0 = 0; c0 < H1; c0 += 32) {
            __syncthreads();
#pragma unroll
            for (int j = 0; j < 4; j++) {
                float v = p_w[((size_t)b * H1 + c0 + ty + 8 * j) * H2 + o0 + tx];
                tile[ty + 8 * j][tx] = v;
                s += v * v;                    // partial ||p_w[b,:,o0+tx]||^2
            }
            __syncthreads();
            float pg = p_g[(size_t)b * H1 + c0 + tx];
#pragma unroll
            for (int j = 0; j < 4; j++) {
                int o = o0 + ty + 8 * j;
                pwTu[((size_t)b * H2 + o) * H1 + c0 + tx] = f2bf(tile[tx][ty + 8 * j] * pg);
            }
        }
        red[ty][tx] = s;
        __syncthreads();
        if (ty == 0) {
            float t = 0.f;
#pragma unroll
            for (int r = 0; r < 8; r++) t += red[r][tx];
            inv_np[(size_t)b * H2 + o0 + tx] = rsqrtf(fmaxf(t, 1e-24f));
        }
    } else if (blk < NB_TPW + NB_CVT) {
        // --- f32 -> bf16 cvt, three concatenated ranges ---
        int i = (blk - NB_TPW) * 256 + threadIdx.x;
        const int n0 = BCNT * TT * DIN / 4, n1 = H1 * DIN / 4;
        const float* s; unsigned short* d; int j = i;
        if (i < n0) { s = input; d = inbf; }
        else if ((j = i - n0) < n1) { s = w1_w; d = w1bf; }
        else { j = i - n0 - n1; s = w2_w; d = w2bf; }
        float4 v = ((const float4*)s)[j];
        ushort4 o;
        o.x = f2bf(v.x); o.y = f2bf(v.y); o.z = f2bf(v.z); o.w = f2bf(v.w);
        ((ushort4*)d)[j] = o;
    } else {
        // --- per-(b,k) tap norm of d_w over channels ---
        const int idx = blk - NB_TPW - NB_CVT;   // b*KW + k
        const int b = idx / KW, k = idx % KW;
        float s = 0.f;
        for (int c = threadIdx.x; c < H1; c += 256) {
            float v = d_w[((size_t)b * H1 + c) * KW + k];
            s += v * v;
        }
        __shared__ float red1[256];
        red1[threadIdx.x] = s; __syncthreads();
        for (int st = 128; st > 0; st >>= 1) {
            if (threadIdx.x < st) red1[threadIdx.x] += red1[threadIdx.x + st];
            __syncthreads();
        }
        if (threadIdx.x == 0) norm_d[idx] = fmaxf(sqrtf(red1[0]), 1e-12f);
    }
}

// depthwise conv along T, sliding window; 2 channels/thread; kernel weights
// computed inline from raw d_w, d_g, norm_d (dwn_s intermediate eliminated)
__global__ __launch_bounds__(256) void k_conv(const unsigned short* __restrict__ h,
                                              const float* __restrict__ d_w,
                                              const float* __restrict__ d_g,
                                              const float* __restrict__ norm_d,
                                              const float* __restrict__ d_b,
                                              unsigned short* __restrict__ y) {
    int tid = threadIdx.x;
    int c2 = blockIdx.y * 256 + tid;
    int c = c2 * 2;
    int t0 = blockIdx.x * 64;
    int b = blockIdx.z;
    const ushort2* hb = (const ushort2*)(h + (size_t)b * TT * H1);
    ushort2* yb = (ushort2*)(y + (size_t)b * TT * H1);
    float g0 = d_g[b * H1 + c] * (float)TT, g1 = d_g[b * H1 + c + 1] * (float)TT;
    float k0[KW], k1[KW];
#pragma unroll
    for (int i = 0; i < KW; i++) {
        float inv_n = 1.f / norm_d[b * KW + i];
        k0[i] = d_w[((size_t)b * H1 + c) * KW + i] * inv_n * g0;
        k1[i] = d_w[((size_t)b * H1 + c + 1) * KW + i] * inv_n * g1;
    }
    float db0 = d_b[b * H1 + c], db1 = d_b[b * H1 + c + 1];
    float w0[KW], w1[KW];
#pragma unroll
    for (int i = 0; i < 8; i++) {
        int t = t0 - 4 + i;
        if (t >= 0 && t < TT) {
            ushort2 v = hb[(size_t)t * (H1 / 2) + c2];
            w0[i] = bf2f(v.x); w1[i] = bf2f(v.y);
        } else { w0[i] = 0.f; w1[i] = 0.f; }
    }
    for (int j = 0; j < 64; j++) {
        int t = t0 + j;
        int tl = t + 4;
        if (tl < TT) {
            ushort2 v = hb[(size_t)tl * (H1 / 2) + c2];
            w0[8] = bf2f(v.x); w1[8] = bf2f(v.y);
        } else { w0[8] = 0.f; w1[8] = 0.f; }
        float a0 = db0, a1 = db1;
#pragma unroll
        for (int i = 0; i < KW; i++) { a0 += k0[i] * w0[i]; a1 += k1[i] * w1[i]; }
        ushort2 o; o.x = f2bf(a0); o.y = f2bf(a1);
        yb[(size_t)t * (H1 / 2) + c2] = o;
#pragma unroll
        for (int i = 0; i < 8; i++) { w0[i] = w0[i + 1]; w1[i] = w1[i + 1]; }
    }
}

// ------- bf16 NT MFMA GEMM: 128 x TN tile, BK=64, 256 threads, 4 blocks/CU -------
// C[m,n] = sum_k A[m,k]*B[n,k], bf16 K-contiguous. LDS rows 64 bf16 = 128 B.
// Staging chunk = 8 rows; lane -> (row=lane>>3, slot=lane&7); slot holds global
// col-group slot^(row&7) [XOR swizzle, conflict-free, verified R5/R6].
// TN=128: 4 waves as 2x2, wave=64x64. TN=64: wave=64x32.
// MODE 0: C=bf16(mish(v + bias[n]))
// MODE 1: C=bf16(v*scale[bz*str+n] + bias[bz*str+n])
// MODE 2: C=f32 (v + bias[n] + bf2f(residbf[idx]))
template <int MODE, int SWIZ, int TN>
__global__ __launch_bounds__(256, 4) void gemm_nt(
    const unsigned short* __restrict__ A, const unsigned short* __restrict__ Bm,
    void* __restrict__ Cp, int Kdim, int lda, int ldb, int ldc,
    long sA, long sB, long sC,
    const float* __restrict__ bias, int biasStride,
    const float* __restrict__ scale,
    const unsigned short* __restrict__ residbf) {
    constexpr int WN = TN / 32;                    // B frags per wave (4 or 2)
    __shared__ __attribute__((aligned(16))) unsigned short Al[128 * 64];
    __shared__ __attribute__((aligned(16))) unsigned short Bl[TN * 64];

    const int tid = threadIdx.x;
    const int lane = tid & 63, wv = tid >> 6;      // 4 waves

    int bx, by, bz;
    if constexpr (SWIZ) {
        // G2: 1024 blocks. XCD k owns batches {2k,2k+1}; m-tile fastest.
        int l = blockIdx.x;
        int xcd = l & 7, s = l >> 3;               // s: 0..127
        bz = xcd * 2 + (s >> 6);
        int u = s & 63;
        bx = u & 7; by = u >> 3;
    } else {
        bx = blockIdx.x; by = blockIdx.y; bz = blockIdx.z;
    }
    const int bm = bx * 128, bn = by * TN;

    const unsigned short* Ab = A + (size_t)sA * bz;
    const unsigned short* Bb = Bm + (size_t)sB * bz;

    // staging lane map (XOR swizzle on source column)
    const int rS = lane >> 3;                       // row within 8-row chunk
    const int cS = ((lane & 7) ^ (rS & 7)) * 8;     // global col-group offset (elems)

    const int wm = (wv >> 1) * 64, wn = (wv & 1) * (TN / 2);
    const int l16 = lane & 15, quad = lane >> 4;
    const int fx = l16 & 7;                         // read-side XOR key

    f32x4 acc[4][WN];
#pragma unroll
    for (int i = 0; i < 4; i++)
#pragma unroll
        for (int j = 0; j < WN; j++)
#pragma unroll
            for (int r = 0; r < 4; r++) acc[i][j][r] = 0.f;

    const int ktiles = Kdim / 64;
    for (int kt = 0; kt < ktiles; ++kt) {
        const int kofs = kt * 64 + cS;
#pragma unroll
        for (int i = 0; i < 4; i++) {
            const int ch = i * 4 + wv;
            const unsigned short* ga = Ab + (size_t)(bm + ch * 8 + rS) * lda + kofs;
            __builtin_amdgcn_global_load_lds((gas_ptr)ga, (lds_ptr)&Al[ch * 512], 16, 0, 0);
        }
#pragma unroll
        for (int i = 0; i < TN / 32; i++) {
            const int ch = i * 4 + wv;
            const unsigned short* gb = Bb + (size_t)(bn + ch * 8 + rS) * ldb + kofs;
            __builtin_amdgcn_global_load_lds((gas_ptr)gb, (lds_ptr)&Bl[ch * 512], 16, 0, 0);
        }
        __syncthreads();

#pragma unroll
        for (int kk = 0; kk < 2; kk++) {
            const int cg = ((kk * 4 + quad) ^ fx) * 8;   // swizzled col offset
            bhalf8 af[4], bf[WN];
#pragma unroll
            for (int mi = 0; mi < 4; mi++)
                af[mi] = *(const bhalf8*)&Al[(wm + mi * 16 + l16) * 64 + cg];
#pragma unroll
            for (int ni = 0; ni < WN; ni++)
                bf[ni] = *(const bhalf8*)&Bl[(wn + ni * 16 + l16) * 64 + cg];
#pragma unroll
            for (int mi = 0; mi < 4; mi++)
#pragma unroll
                for (int ni = 0; ni < WN; ni++)
                    acc[mi][ni] = __builtin_amdgcn_mfma_f32_16x16x32_bf16(af[mi], bf[ni],
                                                                         acc[mi][ni], 0, 0, 0);
        }
        __syncthreads();
    }

    // epilogue: D row = quad*4+r, col = lane&15
#pragma unroll
    for (int mi = 0; mi < 4; mi++)
#pragma unroll
        for (int ni = 0; ni < WN; ni++)
#pragma unroll
            for (int r = 0; r < 4; r++) {
                int gm = bm + wm + mi * 16 + quad * 4 + r;
                int gn = bn + wn + ni * 16 + l16;
                float v = acc[mi][ni][r];
                size_t cidx = (size_t)sC * bz + (size_t)gm * ldc + gn;
                if constexpr (MODE == 0) {
                    v = mish_f(v + bias[gn]);
                    ((unsigned short*)Cp)[cidx] = f2bf(v);
                } else if constexpr (MODE == 1) {
                    size_t si = (size_t)bz * biasStride + gn;
                    v = v * scale[si] + bias[si];
                    ((unsigned short*)Cp)[cidx] = f2bf(v);
                } else {
                    v += bias[gn] + bf2f(residbf[cidx]);
                    ((float*)Cp)[cidx] = v;
                }
            }
}

// ---------------- launch ----------------

extern "C" void kernel_launch(void* const* d_in, const int* in_sizes, int n_in,
                              void* d_out, int out_size, void* d_ws, size_t ws_size,
                              hipStream_t stream) {
    const float* input = (const float*)d_in[0];
    const float* d_w   = (const float*)d_in[1];
    const float* d_g   = (const float*)d_in[2];
    const float* d_b   = (const float*)d_in[3];
    const float* p_w   = (const float*)d_in[4];
    const float* p_g   = (const float*)d_in[5];
    const float* p_b   = (const float*)d_in[6];
    const float* w1_w  = (const float*)d_in[7];
    const float* w1_b  = (const float*)d_in[8];
    const float* w2_w  = (const float*)d_in[9];
    const float* w2_b  = (const float*)d_in[10];
    float* out = (float*)d_out;

    char* ws = (char*)d_ws;
    size_t off = 0;
    auto alloc = [&](size_t bytes) {
        char* p = ws + off;
        off += (bytes + 255) & ~(size_t)255;
        return p;
    };
    float* norm_d        = (float*)alloc((size_t)BCNT * KW * 4);
    float* inv_np        = (float*)alloc((size_t)BCNT * H2 * 4);
    unsigned short* inbf = (unsigned short*)alloc((size_t)BCNT * TT * DIN * 2);
    unsigned short* w1bf = (unsigned short*)alloc((size_t)H1 * DIN * 2);
    unsigned short* w2bf = (unsigned short*)alloc((size_t)DIN * H2 * 2);
    unsigned short* h    = (unsigned short*)alloc((size_t)BCNT * TT * H1 * 2);
    unsigned short* y    = (unsigned short*)alloc((size_t)BCNT * TT * H1 * 2);
    unsigned short* pwTu = (unsigned short*)alloc((size_t)BCNT * H2 * H1 * 2);
    unsigned short* zt   = (unsigned short*)alloc((size_t)BCNT * TT * H2 * 2);

    // PREP: all independent pre-GEMM work in one dispatch (7568 blocks)
    k_prep<<<NB_TPW + NB_CVT + NB_NORM, 256, 0, stream>>>(
        input, inbf, w1_w, w1bf, w2_w, w2bf, p_w, p_g, pwTu, inv_np, d_w, norm_d);

    // G1: h = bf16(mish(input @ w1_w^T + w1_b)), (B*T, H1); 1024 blocks
    gemm_nt<0, 0, 128><<<dim3(BCNT * TT / 128, H1 / 128, 1), 256, 0, stream>>>(
        inbf, w1bf, h, DIN, DIN, DIN, H1, 0, 0, 0, w1_b, 0, nullptr, nullptr);

    // depthwise conv -> y (B*T, H1) bf16 (kernel weights computed inline)
    k_conv<<<dim3(TT / 64, H1 / 512, BCNT), 256, 0, stream>>>(h, d_w, d_g, norm_d, d_b, y);

    // G2 (batched, XCD-swizzled, 1024 blocks): zt = inv_np*(y . pwTu) + p_b
    gemm_nt<1, 1, 128><<<dim3(1024, 1, 1), 256, 0, stream>>>(
        y, pwTu, zt, H1, H1, H1, H2, (long)TT * H1, (long)H2 * H1, (long)TT * H2,
        p_b, H2, inv_np, nullptr);

    // G3: out = zt @ w2^T + w2_b + resid; 128x64 tiles -> 768 blocks
    gemm_nt<2, 0, 64><<<dim3(BCNT * TT / 128, DIN / 64, 1), 256, 0, stream>>>(
        zt, w2bf, out, H2, H2, H2, DIN, 0, 0, 0, w2_b, 0, nullptr, inbf);
}